// Round 7
// baseline (291.026 us; speedup 1.0000x reference)
//
#include <hip/hip_runtime.h>

#define N_NODES 50000
#define N_GRAPHS 128
#define HID 512

// Split-K geometry: Psum[128 x 512] = C[128 x K] * x[K x 512]
#define KSPAN   208                      // 13 k-steps of 16 per block
#define KSPLIT  241                      // 241*208 = 50128 >= 50000; grid = 241
#define KPAD    (KSPAN * KSPLIT)         // 50128
#define NPANEL  (KPAD / 16)              // 3133

// Workspace layout (16B-aligned sections)
#define C8_OFF     0
#define C8_BYTES   ((size_t)N_GRAPHS * KPAD)                 // 6,416,384
#define PSUM_OFF   (C8_OFF + C8_BYTES)
#define PSUM_BYTES ((size_t)N_GRAPHS * HID * 4)              // 262,144
#define COUNTS_OFF (PSUM_OFF + PSUM_BYTES)
#define ZERO_BYTES (COUNTS_OFF + 512)                        // zero C8+Psum+counts
#define APACK_OFF  ZERO_BYTES
#define APACK_BYTES ((size_t)NPANEL * 4 * 64 * 16)           // 12,832,768
#define PART_OFF   (APACK_OFF + APACK_BYTES)
#define PART_BYTES ((size_t)KSPLIT * N_GRAPHS * HID * 4)     // 63.2 MB

typedef __attribute__((ext_vector_type(8))) short bf16x8;
typedef __attribute__((ext_vector_type(16))) float f32x16;
typedef const __attribute__((address_space(1))) void* gas_t;
typedef __attribute__((address_space(3))) void* las_t;

// ---------------------------------------------------------------------------
// Build byte-packed counts C8[g][node] (row stride KPAD) + per-graph path
// counts via LDS histogram.
// ---------------------------------------------------------------------------
__global__ __launch_bounds__(256)
void build_c_kernel(const int* __restrict__ w2, const int* __restrict__ w3,
                    const int* __restrict__ w4, const int* __restrict__ batch,
                    unsigned int* __restrict__ C32, int* __restrict__ counts) {
    __shared__ int hist[N_GRAPHS];
    const int t = threadIdx.x;
    if (t < N_GRAPHS) hist[t] = 0;
    __syncthreads();
    const int i = blockIdx.x * 256 + t;
    if (i < N_NODES) {
        const int a = w2[i];            // walk2[0][i] — path anchor
        const int g = batch[a];
        atomicAdd(&hist[g], 1);
        unsigned int* row = C32 + (size_t)g * (KPAD / 4);
        int nn[12];
        nn[0]  = a;
        nn[1]  = w2[N_NODES + i];
        nn[2]  = w2[2 * N_NODES + i];
        nn[3]  = w3[i];
        nn[4]  = w3[N_NODES + i];
        nn[5]  = w3[2 * N_NODES + i];
        nn[6]  = w3[3 * N_NODES + i];
        nn[7]  = w4[i];
        nn[8]  = w4[N_NODES + i];
        nn[9]  = w4[2 * N_NODES + i];
        nn[10] = w4[3 * N_NODES + i];
        nn[11] = w4[4 * N_NODES + i];
#pragma unroll
        for (int j = 0; j < 12; ++j) {
            const int nd = nn[j];
            atomicAdd(&row[nd >> 2], 1u << ((nd & 3) * 8));
        }
    }
    __syncthreads();
    if (t < N_GRAPHS) { const int hv = hist[t]; if (hv) atomicAdd(&counts[t], hv); }
}

__device__ inline unsigned pack_bf16(unsigned a, unsigned b) {
    // exact: u8 -> f32 -> truncate to bf16 (u8 mantissa fits in bf16)
    return (__builtin_bit_cast(unsigned, (float)a) >> 16) |
           (__builtin_bit_cast(unsigned, (float)b) & 0xFFFF0000u);
}

// ---------------------------------------------------------------------------
// Repack u8 counts into MFMA A-fragment order:
// Apack[(kp*4 + mt)*64 + lane] = 8 bf16 of row (mt*32 + lane&31),
// k = kp*16 + 8*(lane>>5) + 0..7.
// ---------------------------------------------------------------------------
__global__ __launch_bounds__(256)
void c8_to_apack_kernel(const unsigned char* __restrict__ C8,
                        uint4* __restrict__ Apack) {
    const int kp = blockIdx.x;           // 0..NPANEL-1
    const int t = threadIdx.x;
    const int mt = t >> 6;
    const int l = t & 63;
    const int row = mt * 32 + (l & 31);
    const int k0 = kp * 16 + 8 * (l >> 5);
    const uint2 b = *(const uint2*)(C8 + (size_t)row * KPAD + k0);
    uint4 o;
    o.x = pack_bf16(b.x & 0xFFu, (b.x >> 8) & 0xFFu);
    o.y = pack_bf16((b.x >> 16) & 0xFFu, b.x >> 24);
    o.z = pack_bf16(b.y & 0xFFu, (b.y >> 8) & 0xFFu);
    o.w = pack_bf16((b.y >> 16) & 0xFFu, b.y >> 24);
    Apack[(size_t)(kp * 4 + mt) * 64 + l] = o;
}

// one v_perm per dword: result = [hi16(u1) | hi16(u0)] (k-pairwise bf16 pack)
__device__ inline unsigned bpack(unsigned u0, unsigned u1) {
    return __builtin_amdgcn_perm(u1, u0, 0x07060302u);
}

__device__ inline f32x16 mfma_bf16(bf16x8 a, bf16x8 b, f32x16 c) {
    return __builtin_amdgcn_mfma_f32_32x32x16_bf16(a, b, c, 0, 0, 0);
}

// ---------------------------------------------------------------------------
// One ROWS-row chunk: stage wave-private x slice (64 cols) into LDS via
// global_load_lds_dwordx4, prefetch A frags to VGPRs, ONE s_waitcnt(0)
// (no barrier — wave consumes only its own staging), then ROWS/16 MFMA
// k-steps. The 8 waves' staging bursts temporally interleave to cover
// full 2 KB x rows -> sequential DRAM pages.
// ---------------------------------------------------------------------------
template <int ROWS>
__device__ inline void do_chunk(const float* __restrict__ x,
                                const uint4* __restrict__ Apack,
                                float* __restrict__ lb,   // wave-private LDS
                                int w, int lane, int s0, int kp0,
                                f32x16 (&acc)[4][2]) {
    const int cg = w * 64 + (lane & 15) * 4;   // global col of this lane's float4
    const int rsub = lane >> 4;                // row-within-group 0..3

    if (s0 + ROWS <= N_NODES) {
#pragma unroll
        for (int i = 0; i < ROWS / 4; ++i) {
            const float* gp = x + (size_t)(s0 + 4 * i + rsub) * HID + cg;
            las_t lp = (las_t)(lb + 4 * i * 64);
            __builtin_amdgcn_global_load_lds((gas_t)gp, lp, 16, 0, 0);
        }
    } else {                                    // tail: clamp rows (A is 0 there)
#pragma unroll
        for (int i = 0; i < ROWS / 4; ++i) {
            const int row = min(s0 + 4 * i + rsub, N_NODES - 1);
            const float4 v = *(const float4*)(x + (size_t)row * HID + cg);
            *(float4*)(lb + (4 * i + rsub) * 64 + (lane & 15) * 4) = v;
        }
    }

    uint4 a[ROWS / 16][4];
#pragma unroll
    for (int s2 = 0; s2 < ROWS / 16; ++s2)
#pragma unroll
        for (int mt = 0; mt < 4; ++mt)
            a[s2][mt] = Apack[(size_t)((kp0 + s2) * 4 + mt) * 64 + lane];

    __builtin_amdgcn_s_waitcnt(0);   // drain staging DMA + A loads (+ lgkm)

    const int n = lane & 31;
    const int h = lane >> 5;
#pragma unroll
    for (int s2 = 0; s2 < ROWS / 16; ++s2) {
        unsigned b0w[4], b1w[4];
#pragma unroll
        for (int jj = 0; jj < 4; ++jj) {
            const int r0 = s2 * 16 + 8 * h + 2 * jj;
            const unsigned u00 = __builtin_bit_cast(unsigned, lb[r0 * 64 + n]);
            const unsigned u01 = __builtin_bit_cast(unsigned, lb[(r0 + 1) * 64 + n]);
            const unsigned u10 = __builtin_bit_cast(unsigned, lb[r0 * 64 + 32 + n]);
            const unsigned u11 = __builtin_bit_cast(unsigned, lb[(r0 + 1) * 64 + 32 + n]);
            b0w[jj] = bpack(u00, u01);
            b1w[jj] = bpack(u10, u11);
        }
        const bf16x8 B0 = __builtin_bit_cast(bf16x8, make_uint4(b0w[0], b0w[1], b0w[2], b0w[3]));
        const bf16x8 B1 = __builtin_bit_cast(bf16x8, make_uint4(b1w[0], b1w[1], b1w[2], b1w[3]));
#pragma unroll
        for (int mt = 0; mt < 4; ++mt) {
            const bf16x8 af = __builtin_bit_cast(bf16x8, a[s2][mt]);
            acc[mt][0] = mfma_bf16(af, B0, acc[mt][0]);
            acc[mt][1] = mfma_bf16(af, B1, acc[mt][1]);
        }
    }
}

// ---------------------------------------------------------------------------
// Full-row streaming split-K MFMA GEMM. grid = KSPLIT blocks x 512 threads
// (8 waves, 1 block/CU, 2 waves/SIMD -> 256 VGPR cap). Block computes the
// ENTIRE 128x512 output for k-slice [bid*208, +208): x rows are read fully
// and exactly once, sequentially. Wave w owns cols w*64..w*64+63 (4 m-tiles
// x 2 n-subs = 8 acc tiles). No __syncthreads anywhere in the K-loop.
// ---------------------------------------------------------------------------
template <int ATOMIC>
__global__ __launch_bounds__(512, 2)
void pool_gemm6_kernel(const float* __restrict__ x,
                       const uint4* __restrict__ Apack,
                       float* __restrict__ dst) {
    __shared__ float lbuf[8][32 * 64];   // 8 KB per wave, 64 KB total
    const int t = threadIdx.x;
    const int lane = t & 63;
    const int w = t >> 6;
    float* lb = &lbuf[w][0];

    const int kbase = blockIdx.x * KSPAN;
    const int kp_base = blockIdx.x * 13;

    f32x16 acc[4][2];
#pragma unroll
    for (int mt = 0; mt < 4; ++mt)
#pragma unroll
        for (int q = 0; q < 2; ++q)
#pragma unroll
            for (int r = 0; r < 16; ++r) acc[mt][q][r] = 0.f;

    // 208 rows = 6 chunks of 32 + 1 chunk of 16
#pragma unroll
    for (int ch = 0; ch < 6; ++ch)
        do_chunk<32>(x, Apack, lb, w, lane, kbase + ch * 32, kp_base + ch * 2, acc);
    do_chunk<16>(x, Apack, lb, w, lane, kbase + 192, kp_base + 12, acc);

    // Epilogue: C/D layout col=lane&31, row=(i&3)+8*(i>>2)+4*(lane>>5)
    const int n = lane & 31;
    const int h = lane >> 5;
    float* outp = ATOMIC ? dst : dst + (size_t)blockIdx.x * (N_GRAPHS * HID);
#pragma unroll
    for (int mt = 0; mt < 4; ++mt)
#pragma unroll
        for (int q = 0; q < 2; ++q) {
            const int col = w * 64 + q * 32 + n;
#pragma unroll
            for (int i = 0; i < 16; ++i) {
                const int row = mt * 32 + (i & 3) + 8 * (i >> 2) + 4 * h;
                if (ATOMIC) atomicAdd(&outp[(size_t)row * HID + col], acc[mt][q][i]);
                else        outp[(size_t)row * HID + col] = acc[mt][q][i];
            }
        }
}

// ---------------------------------------------------------------------------
// Psum = sum over KSPLIT partials (coalesced streams)
// ---------------------------------------------------------------------------
__global__ __launch_bounds__(256)
void reduce_part_kernel(const float* __restrict__ part, float* __restrict__ Psum) {
    const int id = blockIdx.x * 256 + threadIdx.x;
    float s0 = 0.f, s1 = 0.f;
    int k = 0;
    for (; k + 2 <= KSPLIT; k += 2) {
        s0 += part[(size_t)k * (N_GRAPHS * HID) + id];
        s1 += part[(size_t)(k + 1) * (N_GRAPHS * HID) + id];
    }
    for (; k < KSPLIT; ++k) s0 += part[(size_t)k * (N_GRAPHS * HID) + id];
    Psum[id] = s0 + s1;
}

// ---------------------------------------------------------------------------
// out[r][c] += sum_k A[r][k] * W[k][c]  (+ 12*mask(r)*bias[c] on k-chunk 0)
// ---------------------------------------------------------------------------
__global__ __launch_bounds__(256)
void layer_gemm_kernel(const float* __restrict__ A, int lda, int scaleA,
                       const float* __restrict__ W,
                       const float* __restrict__ bias,
                       const int* __restrict__ counts,
                       float* __restrict__ out) {
    __shared__ float Alds[16][128];
    const int ct = blockIdx.x, rt = blockIdx.y, ksb = blockIdx.z;
    const int t = threadIdx.x;
    const int cc = ct * 64 + (t & 63);
    const int wv = t >> 6;
    const int k0 = ksb * 128;

    for (int idx = t; idx < 16 * 32; idx += 256) {
        const int rr = idx >> 5;
        const int kk = (idx & 31) * 4;
        const int row = rt * 16 + rr;
        float4 v = *(const float4*)&A[(size_t)row * lda + k0 + kk];
        if (scaleA) {
            const float inv = 1.f / (float)max(counts[row], 1);
            v.x *= inv; v.y *= inv; v.z *= inv; v.w *= inv;
        }
        *(float4*)&Alds[rr][kk] = v;
    }
    __syncthreads();

    const int r0 = rt * 16 + wv * 4;
    float a0 = 0.f, a1 = 0.f, a2 = 0.f, a3 = 0.f;
#pragma unroll 8
    for (int k = 0; k < 128; ++k) {
        const float wval = W[(size_t)(k0 + k) * HID + cc];
        a0 += Alds[wv * 4 + 0][k] * wval;
        a1 += Alds[wv * 4 + 1][k] * wval;
        a2 += Alds[wv * 4 + 2][k] * wval;
        a3 += Alds[wv * 4 + 3][k] * wval;
    }
    if (ksb == 0) {
        const float bc = bias[cc];
        a0 += (counts[r0 + 0] > 0 ? 12.f : 0.f) * bc;
        a1 += (counts[r0 + 1] > 0 ? 12.f : 0.f) * bc;
        a2 += (counts[r0 + 2] > 0 ? 12.f : 0.f) * bc;
        a3 += (counts[r0 + 3] > 0 ? 12.f : 0.f) * bc;
    }
    atomicAdd(&out[(size_t)(r0 + 0) * 1536 + cc], a0);
    atomicAdd(&out[(size_t)(r0 + 1) * 1536 + cc], a1);
    atomicAdd(&out[(size_t)(r0 + 2) * 1536 + cc], a2);
    atomicAdd(&out[(size_t)(r0 + 3) * 1536 + cc], a3);
}

extern "C" void kernel_launch(void* const* d_in, const int* in_sizes, int n_in,
                              void* d_out, int out_size, void* d_ws, size_t ws_size,
                              hipStream_t stream) {
    const float* x     = (const float*)d_in[0];
    const int*   w2    = (const int*)d_in[1];
    const int*   w3    = (const int*)d_in[2];
    const int*   w4    = (const int*)d_in[3];
    const int*   batch = (const int*)d_in[4];
    const float* W0    = (const float*)d_in[5];
    const float* b0    = (const float*)d_in[6];
    const float* W1    = (const float*)d_in[7];
    const float* b1    = (const float*)d_in[8];
    const float* W2    = (const float*)d_in[9];
    const float* b2    = (const float*)d_in[10];
    float* out = (float*)d_out;

    unsigned char* ws  = (unsigned char*)d_ws;
    unsigned int* C32  = (unsigned int*)(ws + C8_OFF);
    float* Psum        = (float*)(ws + PSUM_OFF);
    int* counts        = (int*)(ws + COUNTS_OFF);
    uint4* Apack       = (uint4*)(ws + APACK_OFF);
    float* part        = (float*)(ws + PART_OFF);
    const bool use_part = ws_size >= PART_OFF + PART_BYTES;

    hipMemsetAsync(d_ws, 0, ZERO_BYTES, stream);      // C8 + Psum + counts
    hipMemsetAsync(d_out, 0, (size_t)out_size * 4, stream);

    build_c_kernel<<<(N_NODES + 255) / 256, 256, 0, stream>>>(w2, w3, w4, batch, C32, counts);
    c8_to_apack_kernel<<<NPANEL, 256, 0, stream>>>((const unsigned char*)C32, Apack);

    if (use_part) {
        pool_gemm6_kernel<0><<<KSPLIT, 512, 0, stream>>>(x, Apack, part);
        reduce_part_kernel<<<256, 256, 0, stream>>>(part, Psum);
    } else {
        pool_gemm6_kernel<1><<<KSPLIT, 512, 0, stream>>>(x, Apack, Psum);
    }

    layer_gemm_kernel<<<dim3(8, 8, 4), 256, 0, stream>>>(Psum, HID, 1, W0, b0, counts, out);
    layer_gemm_kernel<<<dim3(8, 8, 4), 256, 0, stream>>>(out, 1536, 0, W1, b1, counts, out + 512);
    layer_gemm_kernel<<<dim3(8, 8, 4), 256, 0, stream>>>(out + 512, 1536, 0, W2, b2, counts, out + 1024);
}

// Round 8
// 287.788 us; speedup vs baseline: 1.0113x; 1.0113x over previous
//
#include <hip/hip_runtime.h>

#define N_NODES 50000
#define N_GRAPHS 128
#define HID 512

// Split-K geometry: Psum[128 x 512] = C[128 x K] * x[K x 512]
#define KSPAN   256                      // 16 k-steps of 16 per block
#define KSPLIT  196                      // 196*256 = 50176 >= 50000
#define KPAD    (KSPAN * KSPLIT)         // 50176
#define NPANEL  (KPAD / 16)              // 3136

// Workspace layout (16B-aligned sections)
#define C8_OFF     0
#define C8_BYTES   ((size_t)N_GRAPHS * KPAD)                 // 6,422,528
#define PSUM_OFF   (C8_OFF + C8_BYTES)
#define PSUM_BYTES ((size_t)N_GRAPHS * HID * 4)              // 262,144
#define COUNTS_OFF (PSUM_OFF + PSUM_BYTES)
#define ZERO_BYTES (COUNTS_OFF + 512)                        // zero C8+Psum+counts
#define APACK_OFF  ZERO_BYTES
#define APACK_BYTES ((size_t)NPANEL * 4 * 64 * 16)           // 12,845,056
#define PART_OFF   (APACK_OFF + APACK_BYTES)
#define PART_BYTES ((size_t)KSPLIT * N_GRAPHS * HID * 4)     // 51.4 MB

typedef __attribute__((ext_vector_type(8))) short bf16x8;
typedef __attribute__((ext_vector_type(16))) float f32x16;

// ---------------------------------------------------------------------------
// Build byte-packed counts C8[g][node] (row stride KPAD) + per-graph path
// counts via LDS histogram.
// ---------------------------------------------------------------------------
__global__ __launch_bounds__(256)
void build_c_kernel(const int* __restrict__ w2, const int* __restrict__ w3,
                    const int* __restrict__ w4, const int* __restrict__ batch,
                    unsigned int* __restrict__ C32, int* __restrict__ counts) {
    __shared__ int hist[N_GRAPHS];
    const int t = threadIdx.x;
    if (t < N_GRAPHS) hist[t] = 0;
    __syncthreads();
    const int i = blockIdx.x * 256 + t;
    if (i < N_NODES) {
        const int a = w2[i];            // walk2[0][i] — path anchor
        const int g = batch[a];
        atomicAdd(&hist[g], 1);
        unsigned int* row = C32 + (size_t)g * (KPAD / 4);
        int nn[12];
        nn[0]  = a;
        nn[1]  = w2[N_NODES + i];
        nn[2]  = w2[2 * N_NODES + i];
        nn[3]  = w3[i];
        nn[4]  = w3[N_NODES + i];
        nn[5]  = w3[2 * N_NODES + i];
        nn[6]  = w3[3 * N_NODES + i];
        nn[7]  = w4[i];
        nn[8]  = w4[N_NODES + i];
        nn[9]  = w4[2 * N_NODES + i];
        nn[10] = w4[3 * N_NODES + i];
        nn[11] = w4[4 * N_NODES + i];
#pragma unroll
        for (int j = 0; j < 12; ++j) {
            const int nd = nn[j];
            atomicAdd(&row[nd >> 2], 1u << ((nd & 3) * 8));
        }
    }
    __syncthreads();
    if (t < N_GRAPHS) { const int hv = hist[t]; if (hv) atomicAdd(&counts[t], hv); }
}

__device__ inline unsigned pack_bf16(unsigned a, unsigned b) {
    // exact: u8 -> f32 -> truncate to bf16 (u8 mantissa fits in bf16)
    return (__builtin_bit_cast(unsigned, (float)a) >> 16) |
           (__builtin_bit_cast(unsigned, (float)b) & 0xFFFF0000u);
}

// ---------------------------------------------------------------------------
// Repack u8 counts into MFMA A-fragment order (32x32x16 shape):
// Apack[(kp*4 + mt)*64 + lane] = 8 bf16 of row (mt*32 + lane&31),
// k = kp*16 + 8*(lane>>5) + 0..7.
// ---------------------------------------------------------------------------
__global__ __launch_bounds__(256)
void c8_to_apack_kernel(const unsigned char* __restrict__ C8,
                        uint4* __restrict__ Apack) {
    const int kp = blockIdx.x;           // 0..NPANEL-1
    const int t = threadIdx.x;
    const int mt = t >> 6;
    const int l = t & 63;
    const int row = mt * 32 + (l & 31);
    const int k0 = kp * 16 + 8 * (l >> 5);
    const uint2 b = *(const uint2*)(C8 + (size_t)row * KPAD + k0);
    uint4 o;
    o.x = pack_bf16(b.x & 0xFFu, (b.x >> 8) & 0xFFu);
    o.y = pack_bf16((b.x >> 16) & 0xFFu, b.x >> 24);
    o.z = pack_bf16(b.y & 0xFFu, (b.y >> 8) & 0xFFu);
    o.w = pack_bf16((b.y >> 16) & 0xFFu, b.y >> 24);
    Apack[(size_t)(kp * 4 + mt) * 64 + l] = o;
}

// one v_perm per dword: result = [hi16(u1) | hi16(u0)] (k-pairwise bf16 pack)
__device__ inline unsigned bpack(unsigned u0, unsigned u1) {
    return __builtin_amdgcn_perm(u1, u0, 0x07060302u);
}

__device__ inline f32x16 mfma_bf16(bf16x8 a, bf16x8 b, f32x16 c) {
    return __builtin_amdgcn_mfma_f32_32x32x16_bf16(a, b, c, 0, 0, 0);
}

// B-load: 8 dwords for one 16-k step. For fixed j, lanes cover 32 consecutive
// cols at rows k0+8h+j -> each instr = 2 full 128B lines, 100% efficiency.
template <int GUARD>
__device__ inline void issue_b7(const float* __restrict__ xp, int krow,
                                unsigned (&u)[8]) {
#pragma unroll
    for (int j = 0; j < 8; ++j) {
        int k = krow + j;
        if (GUARD) k = min(k, N_NODES - 1);   // A is zero beyond N_NODES
        u[j] = __builtin_bit_cast(unsigned, xp[(size_t)k * HID]);
    }
}

template <int GUARD>
__device__ inline void run_k7(const float* __restrict__ xp,
                              const uint4* __restrict__ ldsA,
                              int kbase, int h, int lane,
                              f32x16 (&acc)[4]) {
    unsigned bu[2][8];
    issue_b7<GUARD>(xp, kbase + 8 * h, bu[0]);
    issue_b7<GUARD>(xp, kbase + 16 + 8 * h, bu[1]);
#pragma unroll
    for (int s = 0; s < KSPAN / 16; ++s) {
        const int slot = s & 1;
        uint4 a[4];
#pragma unroll
        for (int mt = 0; mt < 4; ++mt)
            a[mt] = ldsA[(s * 4 + mt) * 64 + lane];
        unsigned d[4];
#pragma unroll
        for (int jj = 0; jj < 4; ++jj)
            d[jj] = bpack(bu[slot][2 * jj], bu[slot][2 * jj + 1]);
        const bf16x8 B = __builtin_bit_cast(bf16x8, make_uint4(d[0], d[1], d[2], d[3]));
        if (s + 2 < KSPAN / 16)
            issue_b7<GUARD>(xp, kbase + (s + 2) * 16 + 8 * h, bu[slot]);
#pragma unroll
        for (int mt = 0; mt < 4; ++mt)
            acc[mt] = mfma_bf16(__builtin_bit_cast(bf16x8, a[mt]), B, acc[mt]);
    }
}

// ---------------------------------------------------------------------------
// High-occupancy split-K MFMA GEMM. grid=(2 col-halves, 196 k-splits),
// block = 512 threads (8 waves). A k-slice (128x256 bf16 = 64 KB) is staged
// to LDS ONCE (single barrier in the kernel); thereafter waves free-run:
// wave w owns cols chalf*256 + w*32 (4 m-tiles of 32x32 acc = 64 VGPR),
// B streamed from global with a 2-deep register pipeline, A-frags via
// ds_read_b128. 16 waves/CU (2 blocks/CU), no K-loop barriers/waitcnt(0).
// ---------------------------------------------------------------------------
template <int ATOMIC>
__global__ __launch_bounds__(512, 4)
void pool_gemm7_kernel(const float* __restrict__ x,
                       const uint4* __restrict__ Apack,
                       float* __restrict__ dst) {
    __shared__ uint4 ldsA[(KSPAN / 16) * 4 * 64];   // 64 KB
    const int t = threadIdx.x;
    const int lane = t & 63;
    const int w = t >> 6;
    const int n = lane & 31;
    const int h = lane >> 5;
    const int chalf = blockIdx.x;
    const int ks = blockIdx.y;
    const int kbase = ks * KSPAN;
    const int kp0 = ks * (KSPAN / 16);

    // Stage A slice into LDS (contiguous copy, 8 uint4 per thread)
    {
        const uint4* src = Apack + (size_t)kp0 * 4 * 64;
#pragma unroll
        for (int i = 0; i < 8; ++i)
            ldsA[t + i * 512] = src[t + i * 512];
    }
    __syncthreads();

    f32x16 acc[4];
#pragma unroll
    for (int mt = 0; mt < 4; ++mt)
#pragma unroll
        for (int r = 0; r < 16; ++r) acc[mt][r] = 0.f;

    const int col = chalf * 256 + w * 32 + n;
    const float* xp = x + col;

    if (kbase + KSPAN <= N_NODES) run_k7<0>(xp, ldsA, kbase, h, lane, acc);
    else                          run_k7<1>(xp, ldsA, kbase, h, lane, acc);

    // Epilogue: C/D layout col=lane&31, row=(i&3)+8*(i>>2)+4*(lane>>5)
    float* outp = ATOMIC ? dst : dst + (size_t)ks * (N_GRAPHS * HID);
#pragma unroll
    for (int mt = 0; mt < 4; ++mt)
#pragma unroll
        for (int i = 0; i < 16; ++i) {
            const int row = mt * 32 + (i & 3) + 8 * (i >> 2) + 4 * h;
            if (ATOMIC) atomicAdd(&outp[(size_t)row * HID + col], acc[mt][i]);
            else        outp[(size_t)row * HID + col] = acc[mt][i];
        }
}

// ---------------------------------------------------------------------------
// Psum = sum over KSPLIT partials (coalesced streams)
// ---------------------------------------------------------------------------
__global__ __launch_bounds__(256)
void reduce_part_kernel(const float* __restrict__ part, float* __restrict__ Psum) {
    const int id = blockIdx.x * 256 + threadIdx.x;
    float s0 = 0.f, s1 = 0.f;
    for (int k = 0; k + 2 <= KSPLIT; k += 2) {
        s0 += part[(size_t)k * (N_GRAPHS * HID) + id];
        s1 += part[(size_t)(k + 1) * (N_GRAPHS * HID) + id];
    }
    Psum[id] = s0 + s1;
}

// ---------------------------------------------------------------------------
// out[r][c] += sum_k A[r][k] * W[k][c]  (+ 12*mask(r)*bias[c] on k-chunk 0)
// ---------------------------------------------------------------------------
__global__ __launch_bounds__(256)
void layer_gemm_kernel(const float* __restrict__ A, int lda, int scaleA,
                       const float* __restrict__ W,
                       const float* __restrict__ bias,
                       const int* __restrict__ counts,
                       float* __restrict__ out) {
    __shared__ float Alds[16][128];
    const int ct = blockIdx.x, rt = blockIdx.y, ksb = blockIdx.z;
    const int t = threadIdx.x;
    const int cc = ct * 64 + (t & 63);
    const int wv = t >> 6;
    const int k0 = ksb * 128;

    for (int idx = t; idx < 16 * 32; idx += 256) {
        const int rr = idx >> 5;
        const int kk = (idx & 31) * 4;
        const int row = rt * 16 + rr;
        float4 v = *(const float4*)&A[(size_t)row * lda + k0 + kk];
        if (scaleA) {
            const float inv = 1.f / (float)max(counts[row], 1);
            v.x *= inv; v.y *= inv; v.z *= inv; v.w *= inv;
        }
        *(float4*)&Alds[rr][kk] = v;
    }
    __syncthreads();

    const int r0 = rt * 16 + wv * 4;
    float a0 = 0.f, a1 = 0.f, a2 = 0.f, a3 = 0.f;
#pragma unroll 8
    for (int k = 0; k < 128; ++k) {
        const float wval = W[(size_t)(k0 + k) * HID + cc];
        a0 += Alds[wv * 4 + 0][k] * wval;
        a1 += Alds[wv * 4 + 1][k] * wval;
        a2 += Alds[wv * 4 + 2][k] * wval;
        a3 += Alds[wv * 4 + 3][k] * wval;
    }
    if (ksb == 0) {
        const float bc = bias[cc];
        a0 += (counts[r0 + 0] > 0 ? 12.f : 0.f) * bc;
        a1 += (counts[r0 + 1] > 0 ? 12.f : 0.f) * bc;
        a2 += (counts[r0 + 2] > 0 ? 12.f : 0.f) * bc;
        a3 += (counts[r0 + 3] > 0 ? 12.f : 0.f) * bc;
    }
    atomicAdd(&out[(size_t)(r0 + 0) * 1536 + cc], a0);
    atomicAdd(&out[(size_t)(r0 + 1) * 1536 + cc], a1);
    atomicAdd(&out[(size_t)(r0 + 2) * 1536 + cc], a2);
    atomicAdd(&out[(size_t)(r0 + 3) * 1536 + cc], a3);
}

extern "C" void kernel_launch(void* const* d_in, const int* in_sizes, int n_in,
                              void* d_out, int out_size, void* d_ws, size_t ws_size,
                              hipStream_t stream) {
    const float* x     = (const float*)d_in[0];
    const int*   w2    = (const int*)d_in[1];
    const int*   w3    = (const int*)d_in[2];
    const int*   w4    = (const int*)d_in[3];
    const int*   batch = (const int*)d_in[4];
    const float* W0    = (const float*)d_in[5];
    const float* b0    = (const float*)d_in[6];
    const float* W1    = (const float*)d_in[7];
    const float* b1    = (const float*)d_in[8];
    const float* W2    = (const float*)d_in[9];
    const float* b2    = (const float*)d_in[10];
    float* out = (float*)d_out;

    unsigned char* ws  = (unsigned char*)d_ws;
    unsigned int* C32  = (unsigned int*)(ws + C8_OFF);
    float* Psum        = (float*)(ws + PSUM_OFF);
    int* counts        = (int*)(ws + COUNTS_OFF);
    uint4* Apack       = (uint4*)(ws + APACK_OFF);
    float* part        = (float*)(ws + PART_OFF);
    const bool use_part = ws_size >= PART_OFF + PART_BYTES;

    hipMemsetAsync(d_ws, 0, ZERO_BYTES, stream);      // C8 + Psum + counts
    hipMemsetAsync(d_out, 0, (size_t)out_size * 4, stream);

    build_c_kernel<<<(N_NODES + 255) / 256, 256, 0, stream>>>(w2, w3, w4, batch, C32, counts);
    c8_to_apack_kernel<<<NPANEL, 256, 0, stream>>>((const unsigned char*)C32, Apack);

    if (use_part) {
        pool_gemm7_kernel<0><<<dim3(2, KSPLIT), 512, 0, stream>>>(x, Apack, part);
        reduce_part_kernel<<<256, 256, 0, stream>>>(part, Psum);
    } else {
        pool_gemm7_kernel<1><<<dim3(2, KSPLIT), 512, 0, stream>>>(x, Apack, Psum);
    }

    layer_gemm_kernel<<<dim3(8, 8, 4), 256, 0, stream>>>(Psum, HID, 1, W0, b0, counts, out);
    layer_gemm_kernel<<<dim3(8, 8, 4), 256, 0, stream>>>(out, 1536, 0, W1, b1, counts, out + 512);
    layer_gemm_kernel<<<dim3(8, 8, 4), 256, 0, stream>>>(out + 512, 1536, 0, W2, b2, counts, out + 1024);
}

// Round 9
// 271.900 us; speedup vs baseline: 1.0703x; 1.0584x over previous
//
#include <hip/hip_runtime.h>

#define N_NODES 50000
#define N_GRAPHS 128
#define HID 512

// Split-K geometry: Psum[128 x 512] = C[128 x K] * x[K x 512]
#define KSPAN   208                      // 13 k-steps of 16 per block
#define KSPLIT  241                      // 241*208 = 50128 >= 50000; grid = 241
#define KPAD    (KSPAN * KSPLIT)         // 50128
#define NPANEL  (KPAD / 16)              // 3133

// Workspace layout (16B-aligned sections)
#define C8_OFF     0
#define C8_BYTES   ((size_t)N_GRAPHS * KPAD)                 // 6,416,384
#define PSUM_OFF   (C8_OFF + C8_BYTES)
#define PSUM_BYTES ((size_t)N_GRAPHS * HID * 4)              // 262,144
#define COUNTS_OFF (PSUM_OFF + PSUM_BYTES)
#define ZERO_BYTES (COUNTS_OFF + 512)                        // zero C8+Psum+counts
#define APACK_OFF  ZERO_BYTES
#define APACK_BYTES ((size_t)NPANEL * 4 * 64 * 16)           // 12,832,768
#define PART_OFF   (APACK_OFF + APACK_BYTES)
#define PART_BYTES ((size_t)KSPLIT * N_GRAPHS * HID * 4)     // 61.7 MB

typedef __attribute__((ext_vector_type(8))) short bf16x8;
typedef __attribute__((ext_vector_type(16))) float f32x16;

// ---------------------------------------------------------------------------
// Build byte-packed counts C8[g][node] (row stride KPAD) + per-graph path
// counts via LDS histogram.
// ---------------------------------------------------------------------------
__global__ __launch_bounds__(256)
void build_c_kernel(const int* __restrict__ w2, const int* __restrict__ w3,
                    const int* __restrict__ w4, const int* __restrict__ batch,
                    unsigned int* __restrict__ C32, int* __restrict__ counts) {
    __shared__ int hist[N_GRAPHS];
    const int t = threadIdx.x;
    if (t < N_GRAPHS) hist[t] = 0;
    __syncthreads();
    const int i = blockIdx.x * 256 + t;
    if (i < N_NODES) {
        const int a = w2[i];            // walk2[0][i] — path anchor
        const int g = batch[a];
        atomicAdd(&hist[g], 1);
        unsigned int* row = C32 + (size_t)g * (KPAD / 4);
        int nn[12];
        nn[0]  = a;
        nn[1]  = w2[N_NODES + i];
        nn[2]  = w2[2 * N_NODES + i];
        nn[3]  = w3[i];
        nn[4]  = w3[N_NODES + i];
        nn[5]  = w3[2 * N_NODES + i];
        nn[6]  = w3[3 * N_NODES + i];
        nn[7]  = w4[i];
        nn[8]  = w4[N_NODES + i];
        nn[9]  = w4[2 * N_NODES + i];
        nn[10] = w4[3 * N_NODES + i];
        nn[11] = w4[4 * N_NODES + i];
#pragma unroll
        for (int j = 0; j < 12; ++j) {
            const int nd = nn[j];
            atomicAdd(&row[nd >> 2], 1u << ((nd & 3) * 8));
        }
    }
    __syncthreads();
    if (t < N_GRAPHS) { const int hv = hist[t]; if (hv) atomicAdd(&counts[t], hv); }
}

__device__ inline unsigned pack_bf16(unsigned a, unsigned b) {
    // exact: u8 -> f32 -> truncate to bf16 (u8 mantissa fits in bf16)
    return (__builtin_bit_cast(unsigned, (float)a) >> 16) |
           (__builtin_bit_cast(unsigned, (float)b) & 0xFFFF0000u);
}

// ---------------------------------------------------------------------------
// Repack u8 counts into MFMA A-fragment order (32x32x16 shape):
// Apack[(kp*4 + mt)*64 + lane] = 8 bf16 of row (mt*32 + lane&31),
// k = kp*16 + 8*(lane>>5) + 0..7.
// ---------------------------------------------------------------------------
__global__ __launch_bounds__(256)
void c8_to_apack_kernel(const unsigned char* __restrict__ C8,
                        uint4* __restrict__ Apack) {
    const int kp = blockIdx.x;           // 0..NPANEL-1
    const int t = threadIdx.x;
    const int mt = t >> 6;
    const int l = t & 63;
    const int row = mt * 32 + (l & 31);
    const int k0 = kp * 16 + 8 * (l >> 5);
    const uint2 b = *(const uint2*)(C8 + (size_t)row * KPAD + k0);
    uint4 o;
    o.x = pack_bf16(b.x & 0xFFu, (b.x >> 8) & 0xFFu);
    o.y = pack_bf16((b.x >> 16) & 0xFFu, b.x >> 24);
    o.z = pack_bf16(b.y & 0xFFu, (b.y >> 8) & 0xFFu);
    o.w = pack_bf16((b.y >> 16) & 0xFFu, b.y >> 24);
    Apack[(size_t)(kp * 4 + mt) * 64 + l] = o;
}

// one v_perm per dword: result = [hi16(u1) | hi16(u0)] (k-pairwise bf16 pack)
__device__ inline unsigned bpack(unsigned u0, unsigned u1) {
    return __builtin_amdgcn_perm(u1, u0, 0x07060302u);
}

__device__ inline f32x16 mfma_bf16(bf16x8 a, bf16x8 b, f32x16 c) {
    return __builtin_amdgcn_mfma_f32_32x32x16_bf16(a, b, c, 0, 0, 0);
}

// B-load: 8 dwords for one 16-k step. For fixed j, half-wave h covers 32
// consecutive cols at row k+8h+j -> each instr = 2 full 128B lines.
template <int GUARD>
__device__ inline void issue_b(const float* __restrict__ xp, int krow,
                               unsigned (&u)[8]) {
#pragma unroll
    for (int j = 0; j < 8; ++j) {
        int k = krow + j;
        if (GUARD) k = min(k, N_NODES - 1);   // A is zero beyond N_NODES
        u[j] = __builtin_bit_cast(unsigned, xp[(size_t)k * HID]);
    }
}

// 13 k-steps with a 2-deep register B pipeline (16 dwords in flight/wave):
// no barriers, no waitcnt(0) — waves free-run after the single A-stage sync.
template <int GUARD>
__device__ inline void run_k8(const float* __restrict__ xp,
                              const uint4* __restrict__ ldsA,
                              int kbase, int h, int lane,
                              f32x16 (&acc)[4]) {
    unsigned bu[2][8];
    issue_b<GUARD>(xp, kbase + 8 * h, bu[0]);
    issue_b<GUARD>(xp, kbase + 16 + 8 * h, bu[1]);
#pragma unroll
    for (int s = 0; s < 13; ++s) {
        const int slot = s & 1;
        uint4 a[4];
#pragma unroll
        for (int mt = 0; mt < 4; ++mt)
            a[mt] = ldsA[(s * 4 + mt) * 64 + lane];
        unsigned d[4];
#pragma unroll
        for (int jj = 0; jj < 4; ++jj)
            d[jj] = bpack(bu[slot][2 * jj], bu[slot][2 * jj + 1]);
        const bf16x8 B = __builtin_bit_cast(bf16x8, make_uint4(d[0], d[1], d[2], d[3]));
        if (s + 2 < 13)
            issue_b<GUARD>(xp, kbase + (s + 2) * 16 + 8 * h, bu[slot]);
#pragma unroll
        for (int mt = 0; mt < 4; ++mt)
            acc[mt] = mfma_bf16(__builtin_bit_cast(bf16x8, a[mt]), B, acc[mt]);
    }
}

// ---------------------------------------------------------------------------
// Single-pass split-K MFMA GEMM. grid = 241 blocks x 1024 threads (16 waves,
// 1 block/CU, 4 waves/SIMD). Block computes the ENTIRE 128x512 output for
// k-slice [bid*208, +208): x is read exactly once chip-wide; the A-slice
// (13 panels x 4 KB = 53 KB) is LDS-staged once (single barrier), read via
// conflict-free ds_read_b128. Wave w owns all 128 graphs x 32 cols
// (4 m-tiles of 32x32 acc = 64 VGPR).
// ---------------------------------------------------------------------------
template <int ATOMIC>
__global__ __launch_bounds__(1024, 4)
void pool_gemm8_kernel(const float* __restrict__ x,
                       const uint4* __restrict__ Apack,
                       float* __restrict__ dst) {
    __shared__ uint4 ldsA[13 * 4 * 64];   // 53,248 B
    const int t = threadIdx.x;
    const int lane = t & 63;
    const int w = t >> 6;                 // 0..15
    const int n = lane & 31;
    const int h = lane >> 5;
    const int ks = blockIdx.x;
    const int kbase = ks * KSPAN;

    // Stage A slice into LDS (contiguous copy)
    {
        const uint4* src = Apack + (size_t)(ks * 13) * 4 * 64;
        for (int i = t; i < 13 * 4 * 64; i += 1024)
            ldsA[i] = src[i];
    }
    __syncthreads();

    f32x16 acc[4];
#pragma unroll
    for (int mt = 0; mt < 4; ++mt)
#pragma unroll
        for (int r = 0; r < 16; ++r) acc[mt][r] = 0.f;

    const int col = w * 32 + n;
    const float* xp = x + col;

    if (kbase + KSPAN <= N_NODES) run_k8<0>(xp, ldsA, kbase, h, lane, acc);
    else                          run_k8<1>(xp, ldsA, kbase, h, lane, acc);

    // Epilogue: C/D layout col=lane&31, row=(i&3)+8*(i>>2)+4*(lane>>5)
    float* outp = ATOMIC ? dst : dst + (size_t)ks * (N_GRAPHS * HID);
#pragma unroll
    for (int mt = 0; mt < 4; ++mt)
#pragma unroll
        for (int i = 0; i < 16; ++i) {
            const int row = mt * 32 + (i & 3) + 8 * (i >> 2) + 4 * h;
            if (ATOMIC) atomicAdd(&outp[(size_t)row * HID + col], acc[mt][i]);
            else        outp[(size_t)row * HID + col] = acc[mt][i];
        }
}

// ---------------------------------------------------------------------------
// Psum += partial sums over KSPLIT slices. 2-stage parallel: grid (256, 4),
// blockIdx.y covers ~61 slices; one atomicAdd per element per y-slab into
// the zeroed Psum. 4096 waves -> 16/CU.
// ---------------------------------------------------------------------------
__global__ __launch_bounds__(256)
void reduce_part_kernel(const float* __restrict__ part, float* __restrict__ Psum) {
    const int id = blockIdx.x * 256 + threadIdx.x;
    const int kstart = blockIdx.y * 61;
    const int kend = min(KSPLIT, kstart + 61);
    float s0 = 0.f, s1 = 0.f, s2 = 0.f, s3 = 0.f;
    int k = kstart;
    for (; k + 4 <= kend; k += 4) {
        s0 += part[(size_t)k * (N_GRAPHS * HID) + id];
        s1 += part[(size_t)(k + 1) * (N_GRAPHS * HID) + id];
        s2 += part[(size_t)(k + 2) * (N_GRAPHS * HID) + id];
        s3 += part[(size_t)(k + 3) * (N_GRAPHS * HID) + id];
    }
    for (; k < kend; ++k) s0 += part[(size_t)k * (N_GRAPHS * HID) + id];
    atomicAdd(&Psum[id], (s0 + s1) + (s2 + s3));
}

// ---------------------------------------------------------------------------
// out[r][c] += sum_k A[r][k] * W[k][c]  (+ 12*mask(r)*bias[c] on k-chunk 0)
// ---------------------------------------------------------------------------
__global__ __launch_bounds__(256)
void layer_gemm_kernel(const float* __restrict__ A, int lda, int scaleA,
                       const float* __restrict__ W,
                       const float* __restrict__ bias,
                       const int* __restrict__ counts,
                       float* __restrict__ out) {
    __shared__ float Alds[16][128];
    const int ct = blockIdx.x, rt = blockIdx.y, ksb = blockIdx.z;
    const int t = threadIdx.x;
    const int cc = ct * 64 + (t & 63);
    const int wv = t >> 6;
    const int k0 = ksb * 128;

    for (int idx = t; idx < 16 * 32; idx += 256) {
        const int rr = idx >> 5;
        const int kk = (idx & 31) * 4;
        const int row = rt * 16 + rr;
        float4 v = *(const float4*)&A[(size_t)row * lda + k0 + kk];
        if (scaleA) {
            const float inv = 1.f / (float)max(counts[row], 1);
            v.x *= inv; v.y *= inv; v.z *= inv; v.w *= inv;
        }
        *(float4*)&Alds[rr][kk] = v;
    }
    __syncthreads();

    const int r0 = rt * 16 + wv * 4;
    float a0 = 0.f, a1 = 0.f, a2 = 0.f, a3 = 0.f;
#pragma unroll 8
    for (int k = 0; k < 128; ++k) {
        const float wval = W[(size_t)(k0 + k) * HID + cc];
        a0 += Alds[wv * 4 + 0][k] * wval;
        a1 += Alds[wv * 4 + 1][k] * wval;
        a2 += Alds[wv * 4 + 2][k] * wval;
        a3 += Alds[wv * 4 + 3][k] * wval;
    }
    if (ksb == 0) {
        const float bc = bias[cc];
        a0 += (counts[r0 + 0] > 0 ? 12.f : 0.f) * bc;
        a1 += (counts[r0 + 1] > 0 ? 12.f : 0.f) * bc;
        a2 += (counts[r0 + 2] > 0 ? 12.f : 0.f) * bc;
        a3 += (counts[r0 + 3] > 0 ? 12.f : 0.f) * bc;
    }
    atomicAdd(&out[(size_t)(r0 + 0) * 1536 + cc], a0);
    atomicAdd(&out[(size_t)(r0 + 1) * 1536 + cc], a1);
    atomicAdd(&out[(size_t)(r0 + 2) * 1536 + cc], a2);
    atomicAdd(&out[(size_t)(r0 + 3) * 1536 + cc], a3);
}

extern "C" void kernel_launch(void* const* d_in, const int* in_sizes, int n_in,
                              void* d_out, int out_size, void* d_ws, size_t ws_size,
                              hipStream_t stream) {
    const float* x     = (const float*)d_in[0];
    const int*   w2    = (const int*)d_in[1];
    const int*   w3    = (const int*)d_in[2];
    const int*   w4    = (const int*)d_in[3];
    const int*   batch = (const int*)d_in[4];
    const float* W0    = (const float*)d_in[5];
    const float* b0    = (const float*)d_in[6];
    const float* W1    = (const float*)d_in[7];
    const float* b1    = (const float*)d_in[8];
    const float* W2    = (const float*)d_in[9];
    const float* b2    = (const float*)d_in[10];
    float* out = (float*)d_out;

    unsigned char* ws  = (unsigned char*)d_ws;
    unsigned int* C32  = (unsigned int*)(ws + C8_OFF);
    float* Psum        = (float*)(ws + PSUM_OFF);
    int* counts        = (int*)(ws + COUNTS_OFF);
    uint4* Apack       = (uint4*)(ws + APACK_OFF);
    float* part        = (float*)(ws + PART_OFF);
    const bool use_part = ws_size >= PART_OFF + PART_BYTES;

    hipMemsetAsync(d_ws, 0, ZERO_BYTES, stream);      // C8 + Psum + counts
    hipMemsetAsync(d_out, 0, (size_t)out_size * 4, stream);

    build_c_kernel<<<(N_NODES + 255) / 256, 256, 0, stream>>>(w2, w3, w4, batch, C32, counts);
    c8_to_apack_kernel<<<NPANEL, 256, 0, stream>>>((const unsigned char*)C32, Apack);

    if (use_part) {
        pool_gemm8_kernel<0><<<KSPLIT, 1024, 0, stream>>>(x, Apack, part);
        reduce_part_kernel<<<dim3(256, 4), 256, 0, stream>>>(part, Psum);
    } else {
        pool_gemm8_kernel<1><<<KSPLIT, 1024, 0, stream>>>(x, Apack, Psum);
    }

    layer_gemm_kernel<<<dim3(8, 8, 4), 256, 0, stream>>>(Psum, HID, 1, W0, b0, counts, out);
    layer_gemm_kernel<<<dim3(8, 8, 4), 256, 0, stream>>>(out, 1536, 0, W1, b1, counts, out + 512);
    layer_gemm_kernel<<<dim3(8, 8, 4), 256, 0, stream>>>(out + 512, 1536, 0, W2, b2, counts, out + 1024);
}